// Round 3
// 188.762 us; speedup vs baseline: 1.1763x; 1.1763x over previous
//
#include <hip/hip_runtime.h>

typedef _Float16 f16x8 __attribute__((ext_vector_type(8)));
typedef _Float16 f16x4 __attribute__((ext_vector_type(4)));
typedef __fp16 h16x2 __attribute__((ext_vector_type(2)));  // cvt_pkrtz native type
typedef float f32x4 __attribute__((ext_vector_type(4)));

#define HH 2000
#define WW 1000
#define HWSZ (HH * WW)
#define NEG_INF (-3.0e38f)

// ---- monotone float<->uint encoding for atomicMax on floats ----
// fenc never returns 0 (nonneg -> MSB set; neg -> ~u, zero only for -NaN),
// so buckets can be initialized with a plain memset(0).
__device__ __forceinline__ unsigned fenc(float f) {
    unsigned u = __float_as_uint(f);
    return (u & 0x80000000u) ? ~u : (u | 0x80000000u);
}
__device__ __forceinline__ float fdec(unsigned k) {
    unsigned u = (k & 0x80000000u) ? (k & 0x7fffffffu) : ~k;
    return __uint_as_float(u);
}

__global__ void decode_buckets(unsigned* __restrict__ buck, int n) {
    int i = blockIdx.x * blockDim.x + threadIdx.x;
    if (i < n) {
        unsigned k = buck[i];
        ((float*)buck)[i] = fdec(k);
    }
}

// MFMA 16x16x32 f16 layouts (gfx950, verified earlier: absmax ~2e-3):
//   A: lane holds A[m=lane&15][k=(lane>>4)*8+j]
//   B: lane holds B[k=(lane>>4)*8+j][n=lane&15]
//   D: lane holds D[row=(lane>>4)*4+reg][col=lane&15]
// A = weights (m = out-ch), B = activations (n = pixel).
// Biases folded in via constant-1 channel (K 9->10, 18->19, 36->37).
//
// R16 = R15 resubmitted (container infra failure, source never ran).
// (a) software prefetch: next iteration's 18 input loads are issued BEFORE
//     the current iteration's compute (explicit double-buffered regs), so the
//     ~900cy streaming-miss latency hides under ~700cy of MFMA/LDS/VALU work
//     instead of being serially exposed 8x per wave.
// (b) packed activation epilogues: v_cvt_pkrtz_f16_f32 + v_pk_max_f16 replace
//     scalar cvt+pack+max (10 ops -> 4 per 4 values), cutting ~30% of VALU
//     issue. RTZ rounding instead of RNE: absmax may rise ~2x (monitored).

__global__ __launch_bounds__(128) void mlp_max_mfma(
    const float* __restrict__ in,
    const float* __restrict__ w1, const float* __restrict__ b1,
    const float* __restrict__ w2, const float* __restrict__ b2,
    const float* __restrict__ w3, const float* __restrict__ b3,
    const float* __restrict__ w4, const float* __restrict__ b4,
    unsigned* __restrict__ rowbuck, unsigned* __restrict__ colbuck) {
    // per wave: 2 row-slots x (buf1[16][40] + buf2[16][40]) halves = 5120 B.
    // stride 40 halves = 80B keeps every b128 16B-aligned. Every byte read
    // is written earlier in the same iteration -> no zero-init needed.
    __shared__ _Float16 lds[2][2 * 1280];
    __shared__ float rowsm[2][16][16];   // [wave][row-in-block][px]

    const int tx = threadIdx.x;   // 0..63
    const int wv = threadIdx.y;   // 0..1 (independent waves)
    const int px = tx & 15;
    const int q = tx >> 4;

    _Float16* s0buf1 = &lds[wv][0];
    _Float16* s0buf2 = &lds[wv][640];
    _Float16* s1buf1 = &lds[wv][1280];
    _Float16* s1buf2 = &lds[wv][1920];

    // ---- weight A-fragments (persistent, reused every iteration) ----
    f16x8 A1[2], A2[3], A3s0[3], A3s1[3];
#pragma unroll
    for (int t = 0; t < 2; ++t) {
        const int m = t * 16 + px;
#pragma unroll
        for (int j = 0; j < 8; ++j) {
            const int k = q * 8 + j;
            float v = 0.f;
            if (m < 18) {
                if (k < 9) v = w1[m * 9 + k];
                else if (k == 9) v = b1[m];
            }
            A1[t][j] = (_Float16)v;
        }
    }
#pragma unroll
    for (int t = 0; t < 3; ++t) {
        const int m = t * 16 + px;
#pragma unroll
        for (int j = 0; j < 8; ++j) {
            const int k = q * 8 + j;
            float v = 0.f;
            if (m < 36) {
                if (k < 18) v = w2[m * 18 + k];
                else if (k == 18) v = b2[m];
            }
            A2[t][j] = (_Float16)v;
        }
    }
#pragma unroll
    for (int t = 0; t < 3; ++t) {
        const int m = t * 16 + px;
#pragma unroll
        for (int j = 0; j < 8; ++j) {
            const int k = q * 8 + j;
            float v = 0.f;
            if (m < 36 && k < 32) v = w3[m * 36 + k];
            A3s0[t][j] = (_Float16)v;
            float v2 = 0.f;
            const int k2 = 32 + k;  // slice 2: ch 32..35 real, 36 = bias
            if (m < 36) {
                if (k2 < 36) v2 = w3[m * 36 + k2];
                else if (k2 == 36) v2 = b3[m];
            }
            A3s1[t][j] = (_Float16)v2;
        }
    }

    float w4r[3][4];
#pragma unroll
    for (int t = 0; t < 3; ++t)
#pragma unroll
        for (int rg = 0; rg < 4; ++rg) {
            const int ch = t * 16 + q * 4 + rg;
            w4r[t][rg] = (ch < 36) ? w4[ch] : 0.f;
        }
    const float b4s = b4[0];

    const int col = blockIdx.x * 32 + wv * 16 + px;
    const int colc = (col < WW) ? col : (WW - 1);
    const bool colok = (col < WW);
    const int rb = blockIdx.y * 16;

    float colmax = NEG_INF;
    const f32x4 zf4 = {0.f, 0.f, 0.f, 0.f};
    const h16x2 z2 = {(__fp16)0.f, (__fp16)0.f};

    const float* pin = in + colc;

    union U8 { f16x8 v; h16x2 h[4]; };
    union U4 { f16x4 v; h16x2 h[2]; };

    // ---- double-buffered raw input regs: [j] for rows (r, r+1) ----
    float ca[8], cb[8], na[8], nb[8];

    auto LOAD = [&](int r, float (&v0)[8], float (&v1)[8]) {
#pragma unroll
        for (int j = 0; j < 8; ++j) {
            const int c = q * 8 + j;
            float x0 = 0.f, x1 = 0.f;
            if (c < 9) {
                x0 = pin[c * HWSZ + r * WW];
                x1 = pin[c * HWSZ + r * WW + WW];
            } else if (c == 9) {
                x0 = 1.f; x1 = 1.f;   // constant-1 bias channel (k=9)
            }
            v0[j] = x0;
            v1[j] = x1;
        }
    };

    auto COMPUTE = [&](int it, const float (&v0)[8], const float (&v1)[8]) {
        // ---- pack inputs to f16 (packed RTZ cvt) ----
        U8 b0u, b1u;
#pragma unroll
        for (int j = 0; j < 4; ++j) {
            b0u.h[j] = __builtin_amdgcn_cvt_pkrtz(v0[2 * j], v0[2 * j + 1]);
            b1u.h[j] = __builtin_amdgcn_cvt_pkrtz(v1[2 * j], v1[2 * j + 1]);
        }
        const f16x8 bin0 = b0u.v;
        const f16x8 bin1 = b1u.v;

        // ---- layer 1 (bias via k=9) ----
        f32x4 D1a[2], D1b[2];
#pragma unroll
        for (int t = 0; t < 2; ++t) {
            D1a[t] = __builtin_amdgcn_mfma_f32_16x16x32_f16(A1[t], bin0, zf4, 0, 0, 0);
            D1b[t] = __builtin_amdgcn_mfma_f32_16x16x32_f16(A1[t], bin1, zf4, 0, 0, 0);
        }
#pragma unroll
        for (int t = 0; t < 2; ++t) {
            U4 h0, h1;
            h0.h[0] = __builtin_elementwise_max(
                __builtin_amdgcn_cvt_pkrtz(D1a[t][0], D1a[t][1]), z2);
            h0.h[1] = __builtin_elementwise_max(
                __builtin_amdgcn_cvt_pkrtz(D1a[t][2], D1a[t][3]), z2);
            h1.h[0] = __builtin_elementwise_max(
                __builtin_amdgcn_cvt_pkrtz(D1b[t][0], D1b[t][1]), z2);
            h1.h[1] = __builtin_elementwise_max(
                __builtin_amdgcn_cvt_pkrtz(D1b[t][2], D1b[t][3]), z2);
            if (t == 1 && q == 0) {  // ch18 = constant-1 bias channel for L2
                h0.v[2] = (_Float16)1.f;
                h1.v[2] = (_Float16)1.f;
            }
            *(f16x4*)&s0buf1[px * 40 + t * 16 + q * 4] = h0.v;
            *(f16x4*)&s1buf1[px * 40 + t * 16 + q * 4] = h1.v;
        }
        const f16x8 B2a = *(const f16x8*)&s0buf1[px * 40 + q * 8];
        const f16x8 B2b = *(const f16x8*)&s1buf1[px * 40 + q * 8];

        // ---- layer 2 (bias via k=18) ----
        f32x4 D2a[3], D2b[3];
#pragma unroll
        for (int t = 0; t < 3; ++t) {
            D2a[t] = __builtin_amdgcn_mfma_f32_16x16x32_f16(A2[t], B2a, zf4, 0, 0, 0);
            D2b[t] = __builtin_amdgcn_mfma_f32_16x16x32_f16(A2[t], B2b, zf4, 0, 0, 0);
        }
#pragma unroll
        for (int t = 0; t < 3; ++t) {
            U4 h0, h1;
            h0.h[0] = __builtin_elementwise_max(
                __builtin_amdgcn_cvt_pkrtz(D2a[t][0], D2a[t][1]), z2);
            h0.h[1] = __builtin_elementwise_max(
                __builtin_amdgcn_cvt_pkrtz(D2a[t][2], D2a[t][3]), z2);
            h1.h[0] = __builtin_elementwise_max(
                __builtin_amdgcn_cvt_pkrtz(D2b[t][0], D2b[t][1]), z2);
            h1.h[1] = __builtin_elementwise_max(
                __builtin_amdgcn_cvt_pkrtz(D2b[t][2], D2b[t][3]), z2);
            if (t < 2) {
                *(f16x4*)&s0buf2[px * 40 + t * 16 + q * 4] = h0.v;
                *(f16x4*)&s1buf2[px * 40 + t * 16 + q * 4] = h1.v;
            } else if (q == 0) {  // ch 32..35 only
                *(f16x4*)&s0buf2[px * 40 + 32] = h0.v;
                *(f16x4*)&s1buf2[px * 40 + 32] = h1.v;
            }
        }
        const f16x8 B3a0 = *(const f16x8*)&s0buf2[px * 40 + q * 8];
        const f16x8 B3b0 = *(const f16x8*)&s1buf2[px * 40 + q * 8];
        f16x8 B3a1 = {0, 0, 0, 0, 0, 0, 0, 0};
        f16x8 B3b1 = {0, 0, 0, 0, 0, 0, 0, 0};
        if (q == 0) {  // slice2: j0..3 = ch32..35, j4 = bias (=1)
            const f16x4 t0 = *(const f16x4*)&s0buf2[px * 40 + 32];
            const f16x4 t1 = *(const f16x4*)&s1buf2[px * 40 + 32];
#pragma unroll
            for (int j = 0; j < 4; ++j) { B3a1[j] = t0[j]; B3b1[j] = t1[j]; }
            B3a1[4] = (_Float16)1.f;
            B3b1[4] = (_Float16)1.f;
        }

        // ---- layer 3 (two K-slices, bias via k=36) ----
        f32x4 D3a[3], D3b[3];
#pragma unroll
        for (int t = 0; t < 3; ++t) {
            D3a[t] = __builtin_amdgcn_mfma_f32_16x16x32_f16(A3s0[t], B3a0, zf4, 0, 0, 0);
            D3a[t] = __builtin_amdgcn_mfma_f32_16x16x32_f16(A3s1[t], B3a1, D3a[t], 0, 0, 0);
            D3b[t] = __builtin_amdgcn_mfma_f32_16x16x32_f16(A3s0[t], B3b0, zf4, 0, 0, 0);
            D3b[t] = __builtin_amdgcn_mfma_f32_16x16x32_f16(A3s1[t], B3b1, D3b[t], 0, 0, 0);
        }

        // ---- layer 4 epilogue: dot + 2 sum-shuffles; row-max via LDS scatter ----
        float sa = 0.f, sb = 0.f;
#pragma unroll
        for (int t = 0; t < 3; ++t)
#pragma unroll
            for (int rg = 0; rg < 4; ++rg) {
                sa = fmaf(w4r[t][rg], fmaxf(D3a[t][rg], 0.f), sa);
                sb = fmaf(w4r[t][rg], fmaxf(D3b[t][rg], 0.f), sb);
            }
        sa += __shfl_xor(sa, 16, 64); sb += __shfl_xor(sb, 16, 64);
        sa += __shfl_xor(sa, 32, 64); sb += __shfl_xor(sb, 32, 64);
        sa += b4s; sb += b4s;

        sa = colok ? sa : NEG_INF;
        sb = colok ? sb : NEG_INF;
        colmax = fmaxf(colmax, fmaxf(sa, sb));

        // every lane holds the full s(px); scatter to [row][px], fire-and-forget.
        // banks: row even->0..15, row odd->16..31 -> 32 active lanes, 0 conflicts.
        if (q == 0) rowsm[wv][it * 2][px] = sa;
        else if (q == 1) rowsm[wv][it * 2 + 1][px] = sb;
    };

    // ---- main loop: prefetch it+1's loads before computing it ----
    LOAD(rb, ca, cb);
#pragma unroll 1
    for (int it = 0; it < 8; it += 2) {
        LOAD(rb + (it + 1) * 2, na, nb);   // prefetch odd half-step
        COMPUTE(it, ca, cb);
        if (it < 6) LOAD(rb + (it + 2) * 2, ca, cb);  // prefetch next even
        COMPUTE(it + 1, na, nb);
    }

    // ---- end-of-wave flush (no barrier: rowsm slice is wave-private) ----
    if (q == 0 && colok) atomicMax(&colbuck[col], fenc(colmax));
    if (tx < 16) {
        const f32x4 v0 = *(const f32x4*)&rowsm[wv][tx][0];
        const f32x4 v1 = *(const f32x4*)&rowsm[wv][tx][4];
        const f32x4 v2 = *(const f32x4*)&rowsm[wv][tx][8];
        const f32x4 v3 = *(const f32x4*)&rowsm[wv][tx][12];
        float m = NEG_INF;
#pragma unroll
        for (int j = 0; j < 4; ++j) {
            m = fmaxf(m, fmaxf(fmaxf(v0[j], v1[j]), fmaxf(v2[j], v3[j])));
        }
        atomicMax(&rowbuck[rb + tx], fenc(m));
    }
}

extern "C" void kernel_launch(void* const* d_in, const int* in_sizes, int n_in,
                              void* d_out, int out_size, void* d_ws, size_t ws_size,
                              hipStream_t stream) {
    const float* in = (const float*)d_in[0];
    // d_in[1] = T_out (unused), d_in[2] = T_indices (identity, unused)
    const float* w1 = (const float*)d_in[3];
    const float* b1 = (const float*)d_in[4];
    const float* w2 = (const float*)d_in[5];
    const float* b2 = (const float*)d_in[6];
    const float* w3 = (const float*)d_in[7];
    const float* b3 = (const float*)d_in[8];
    const float* w4 = (const float*)d_in[9];
    const float* b4 = (const float*)d_in[10];

    unsigned* buck = (unsigned*)d_out;  // [0,2000) row maxes, [2000,3000) col maxes

    // fenc never produces 0, so memset-0 is a valid atomicMax identity.
    (void)hipMemsetAsync(buck, 0, 3000 * sizeof(unsigned), stream);

    dim3 block(64, 2);
    dim3 grid(32, 125);  // 32*32=1024 >= 1000 cols ; 125*16=2000 rows exactly
    mlp_max_mfma<<<grid, block, 0, stream>>>(in, w1, b1, w2, b2, w3, b3, w4, b4,
                                             buck, buck + 2000);

    decode_buckets<<<(3000 + 255) / 256, 256, 0, stream>>>(buck, 3000);
}